// Round 1
// 2180.998 us; speedup vs baseline: 1.1816x; 1.1816x over previous
//
#include <hip/hip_runtime.h>
#include <cfloat>

#define NROWS 131072
#define DIM   256
#define KCB   512
#define RM    64     // rows per workgroup
#define KT    128    // codes per tile (32 code-groups x 4)
#define DC    64     // d-chunk (floats)
#define ZSTR  260    // zs stride: 260 % 32 == 4 -> 2-way bank alias (free)
#define ESTR  68     // es stride: 68 % 32 == 4  -> 2-way bank alias (free)
#define NTHR  512

struct __align__(16) SMem {
    float zs[RM][ZSTR];    // 66560 B  full z-tile (staged ONCE)
    float es[KT][ESTR];    // 34816 B  e-tile d-chunk
    float A[RM];           //   256 B  np.sum(z*z) per row (pairwise-exact)
    float C[KCB];          //  2048 B  np.sum(e*e) per code (pairwise-exact)
    float s1v[RM][32];     //  8192 B
    int   s1i[RM][32];     //  8192 B
    int   bestk[RM];       //   256 B
};                         // 120320 B total -> 1 block/CU, 8 waves/CU

// numpy pairwise_sum over one 128-element block of fl(x*x):
// r[0..7] = w[0..7]; 15 strided add rounds; combine ((r0+r1)+(r2+r3))+((r4+r5)+(r6+r7))
__device__ __forceinline__ float pw128_sq(const float* __restrict__ p)
{
#pragma clang fp contract(off)
    float r[8];
#pragma unroll
    for (int j = 0; j < 8; ++j) { float x = p[j]; r[j] = x * x; }
    for (int i = 8; i < 128; i += 8) {
#pragma unroll
        for (int j = 0; j < 8; ++j) { float x = p[i + j]; r[j] = r[j] + x * x; }
    }
    return ((r[0] + r[1]) + (r[2] + r[3])) + ((r[4] + r[5]) + (r[6] + r[7]));
}

__global__ __launch_bounds__(NTHR, 2)
void vq_np_faithful(const float* __restrict__ z,
                    const float* __restrict__ cb,
                    float* __restrict__ out)
{
#pragma clang fp contract(off)
    __shared__ SMem sm;
    const int tid = threadIdx.x;
    const int tr  = tid & 15;    // row group (16 groups x 4 rows)
    const int tc  = tid >> 4;    // code group (32 groups x 4 codes)
    const int r0  = blockIdx.x * RM;

    // ---- stage FULL z-tile once: 64 rows x 256 floats (z read from HBM exactly once) ----
    {
        const int row = tid >> 3, q0 = tid & 7;
        const float* gz = z + (size_t)(r0 + row) * DIM;
#pragma unroll
        for (int p = 0; p < 8; ++p) {
            int q = q0 + 8 * p;
            *(float4*)(&sm.zs[row][4 * q]) = *(const float4*)(gz + 4 * q);
        }
    }
    // ---- C_k = np.sum(cb*cb, -1): pairwise (128+128), codebook is L2-resident ----
    for (int k = tid; k < KCB; k += NTHR) {
        const float* er = cb + (size_t)k * DIM;
        sm.C[k] = pw128_sq(er) + pw128_sq(er + 128);
    }
    __syncthreads();   // zs staged
    // ---- A_r = np.sum(z*z, -1) from the LDS copy (identical bits to global row) ----
    if (tid < RM) {
        const float* zr = &sm.zs[tid][0];
        sm.A[tid] = pw128_sq(zr) + pw128_sq(zr + 128);
    }

    float bv[4]; int bi[4];
#pragma unroll
    for (int u = 0; u < 4; ++u) { bv[u] = FLT_MAX; bi[u] = 0; }

    for (int ct = 0; ct < KCB / KT; ++ct) {          // 4 code tiles of 128
        // einsum SIMD-lane accumulators: acc[u][v][j], j = SSE lane (d mod 4)
        float acc[4][4][4];
#pragma unroll
        for (int u = 0; u < 4; ++u)
#pragma unroll
            for (int v = 0; v < 4; ++v)
#pragma unroll
                for (int j = 0; j < 4; ++j) acc[u][v][j] = 0.f;

        for (int dc = 0; dc < DIM / DC; ++dc) {      // d-chunks ascending (numpy order)
            __syncthreads();   // previous es readers done
            {   // stage e-tile chunk: 128 rows x 64 floats (raw copy, no rounding)
                const int row = tid >> 2, q0 = tid & 3;
                const float* ge = cb + (size_t)(ct * KT + row) * DIM + dc * DC;
#pragma unroll
                for (int p = 0; p < 4; ++p) {
                    int q = q0 + 4 * p;
                    *(float4*)(&sm.es[row][4 * q]) = *(const float4*)(ge + 4 * q);
                }
            }
            __syncthreads();   // es ready

            // 4 SIMD-blocks of 16 per chunk; numpy chain order within block:
            // vector offsets 12,8,4,0 (reverse-chained), separate mul+add
#pragma unroll
            for (int b = 0; b < 4; ++b) {
                float zb[4][16];
#pragma unroll
                for (int u = 0; u < 4; ++u) {
                    const float* src = &sm.zs[tr + 16 * u][dc * DC + 16 * b];
#pragma unroll
                    for (int q = 0; q < 4; ++q) {
                        float4 t = *(const float4*)(src + 4 * q);
                        zb[u][4*q+0] = t.x; zb[u][4*q+1] = t.y;
                        zb[u][4*q+2] = t.z; zb[u][4*q+3] = t.w;
                    }
                }
#pragma unroll
                for (int v = 0; v < 4; ++v) {        // stream eb one v at a time:
                    float eb[16];                    // live = acc64 + zb64 + eb16
                    const float* src = &sm.es[tc + 32 * v][16 * b];
#pragma unroll
                    for (int q = 0; q < 4; ++q) {
                        float4 t = *(const float4*)(src + 4 * q);
                        eb[4*q+0] = t.x; eb[4*q+1] = t.y;
                        eb[4*q+2] = t.z; eb[4*q+3] = t.w;
                    }
#pragma unroll
                    for (int u = 0; u < 4; ++u)
#pragma unroll
                        for (int qq = 0; qq < 4; ++qq) {
                            const int q = 3 - qq;    // reverse chain: 12,8,4,0
#pragma unroll
                            for (int j = 0; j < 4; ++j) {
                                const int o = 4 * q + j;
                                acc[u][v][j] = acc[u][v][j] + zb[u][o] * eb[o];
                            }
                        }
                }
            }
        }

        // tile epilogue: hsum (SSE3 hadd grouping), dists, running first-min
#pragma unroll
        for (int u = 0; u < 4; ++u)
#pragma unroll
            for (int v = 0; v < 4; ++v) {
                const int k = ct * KT + tc + 32 * v;   // ascending k per thread
                float B = (acc[u][v][0] + acc[u][v][1]) + (acc[u][v][2] + acc[u][v][3]);
                float dist = (sm.A[tr + 16 * u] - 2.0f * B) + sm.C[k];
                if (dist < bv[u]) { bv[u] = dist; bi[u] = k; }   // strict <: first min
            }
    }

    // ---- cross-thread merge per row (index tiebreak = np.argmin first-min) ----
#pragma unroll
    for (int u = 0; u < 4; ++u) {
        const int r = tr + 16 * u;
        sm.s1v[r][tc] = bv[u];
        sm.s1i[r][tc] = bi[u];
    }
    __syncthreads();

    if (tid < RM) {
        float best = sm.s1v[tid][0];
        int   bidx = sm.s1i[tid][0];
        for (int t = 1; t < 32; ++t) {
            float v = sm.s1v[tid][t];
            int   i = sm.s1i[tid][t];
            if (v < best || (v == best && i < bidx)) { best = v; bidx = i; }
        }
        sm.bestk[tid] = bidx;
    }
    __syncthreads();

    // ---- outputs: z_q_st = fl(z + fl(zq - z)), z_q = zq; z comes from LDS copy ----
    {
        const int row = tid >> 3, q0 = tid & 7;
        const int k = sm.bestk[row];
        const float* zr = &sm.zs[row][0];
        const float* ek = cb + (size_t)k * DIM;
        float* o0 = out + (size_t)(r0 + row) * DIM;
        float* o1 = out + (size_t)NROWS * DIM + (size_t)(r0 + row) * DIM;
#pragma unroll
        for (int p = 0; p < 8; ++p) {
            int q = q0 + 8 * p;
            float4 zv = *(const float4*)(zr + 4 * q);
            float4 ev = *(const float4*)(ek + 4 * q);
            float4 st;
            st.x = zv.x + (ev.x - zv.x);
            st.y = zv.y + (ev.y - zv.y);
            st.z = zv.z + (ev.z - zv.z);
            st.w = zv.w + (ev.w - zv.w);
            *(float4*)(o0 + 4 * q) = st;
            *(float4*)(o1 + 4 * q) = ev;
        }
    }
}

extern "C" void kernel_launch(void* const* d_in, const int* in_sizes, int n_in,
                              void* d_out, int out_size, void* d_ws, size_t ws_size,
                              hipStream_t stream) {
    const float* z  = (const float*)d_in[0];   // z_e      [131072, 256] fp32
    const float* cb = (const float*)d_in[1];   // codebook [512, 256]    fp32
    float* out = (float*)d_out;                // (z_q_st, z_q) concat

    dim3 grid(NROWS / RM);
    dim3 block(NTHR);
    vq_np_faithful<<<grid, block, 0, stream>>>(z, cb, out);
}

// Round 3
// 2096.258 us; speedup vs baseline: 1.2294x; 1.0404x over previous
//
#include <hip/hip_runtime.h>
#include <cfloat>

#define NROWS 131072
#define DIM   256
#define KCB   512
#define RM    64     // rows per workgroup
#define KT    128    // codes per tile (32 code-groups x 4)
#define DC    64     // d-chunk (floats)
#define ZSTR  260    // zs stride: 260 % 32 == 4 -> 2-way bank alias (free)
#define ESTR  68     // es stride: 68 % 32 == 4  -> 2-way bank alias (free)
#define NTHR  512

struct __align__(16) SMem {
    float zs[RM][ZSTR];    // 66560 B  full z-tile (staged ONCE)
    float es[KT][ESTR];    // 34816 B  e-tile d-chunk
    float A[RM];           //   256 B  np.sum(z*z) per row (pairwise-exact)
    float C[KCB];          //  2048 B  np.sum(e*e) per code (pairwise-exact)
    float s1v[RM][32];     //  8192 B
    int   s1i[RM][32];     //  8192 B
    int   bestk[RM];       //   256 B
};                         // 120320 B total -> 1 block/CU (LDS-limited), 8 waves/CU

// numpy pairwise_sum over one 128-element block of fl(x*x):
// r[0..7] = w[0..7]; 15 strided add rounds; combine ((r0+r1)+(r2+r3))+((r4+r5)+(r6+r7))
__device__ __forceinline__ float pw128_sq(const float* __restrict__ p)
{
#pragma clang fp contract(off)
    float r[8];
#pragma unroll
    for (int j = 0; j < 8; ++j) { float x = p[j]; r[j] = x * x; }
    for (int i = 8; i < 128; i += 8) {
#pragma unroll
        for (int j = 0; j < 8; ++j) { float x = p[i + j]; r[j] = r[j] + x * x; }
    }
    return ((r[0] + r[1]) + (r[2] + r[3])) + ((r[4] + r[5]) + (r[6] + r[7]));
}

// launch_bounds(512, 1): with (512,2) the observed VGPR cap was 128
// (= 512 regs / 4 waves-per-EU, i.e. 2 blocks/CU semantics) -> ~4GB/dispatch
// of scratch spill traffic while LDS limited us to 1 block/CU anyway.
// With (512,1) the cap is 256 VGPRs (8 waves/CU); live set ~170 fits, no spill.
__global__ __launch_bounds__(NTHR, 1)
void vq_np_faithful(const float* __restrict__ z,
                    const float* __restrict__ cb,
                    float* __restrict__ out)
{
#pragma clang fp contract(off)
    __shared__ SMem sm;
    const int tid = threadIdx.x;
    const int tr  = tid & 15;    // row group (16 groups x 4 rows)
    const int tc  = tid >> 4;    // code group (32 groups x 4 codes)
    const int r0  = blockIdx.x * RM;

    // ---- stage FULL z-tile once: 64 rows x 256 floats (z read from HBM exactly once) ----
    {
        const int row = tid >> 3, q0 = tid & 7;
        const float* gz = z + (size_t)(r0 + row) * DIM;
#pragma unroll
        for (int p = 0; p < 8; ++p) {
            int q = q0 + 8 * p;
            *(float4*)(&sm.zs[row][4 * q]) = *(const float4*)(gz + 4 * q);
        }
    }
    // ---- C_k = np.sum(cb*cb, -1): pairwise (128+128), codebook is L2-resident ----
    for (int k = tid; k < KCB; k += NTHR) {
        const float* er = cb + (size_t)k * DIM;
        sm.C[k] = pw128_sq(er) + pw128_sq(er + 128);
    }
    __syncthreads();   // zs staged
    // ---- A_r = np.sum(z*z, -1) from the LDS copy (identical bits to global row) ----
    if (tid < RM) {
        const float* zr = &sm.zs[tid][0];
        sm.A[tid] = pw128_sq(zr) + pw128_sq(zr + 128);
    }

    float bv[4]; int bi[4];
#pragma unroll
    for (int u = 0; u < 4; ++u) { bv[u] = FLT_MAX; bi[u] = 0; }

    for (int ct = 0; ct < KCB / KT; ++ct) {          // 4 code tiles of 128
        // einsum SIMD-lane accumulators: acc[u][v][j], j = SSE lane (d mod 4)
        float acc[4][4][4];
#pragma unroll
        for (int u = 0; u < 4; ++u)
#pragma unroll
            for (int v = 0; v < 4; ++v)
#pragma unroll
                for (int j = 0; j < 4; ++j) acc[u][v][j] = 0.f;

        for (int dc = 0; dc < DIM / DC; ++dc) {      // d-chunks ascending (numpy order)
            __syncthreads();   // previous es readers done
            {   // stage e-tile chunk: 128 rows x 64 floats (raw copy, no rounding)
                const int row = tid >> 2, q0 = tid & 3;
                const float* ge = cb + (size_t)(ct * KT + row) * DIM + dc * DC;
#pragma unroll
                for (int p = 0; p < 4; ++p) {
                    int q = q0 + 4 * p;
                    *(float4*)(&sm.es[row][4 * q]) = *(const float4*)(ge + 4 * q);
                }
            }
            __syncthreads();   // es ready

            // 4 SIMD-blocks of 16 per chunk; numpy chain order within block:
            // vector offsets 12,8,4,0 (reverse-chained), separate mul+add
#pragma unroll
            for (int b = 0; b < 4; ++b) {
                float zb[4][16];
#pragma unroll
                for (int u = 0; u < 4; ++u) {
                    const float* src = &sm.zs[tr + 16 * u][dc * DC + 16 * b];
#pragma unroll
                    for (int q = 0; q < 4; ++q) {
                        float4 t = *(const float4*)(src + 4 * q);
                        zb[u][4*q+0] = t.x; zb[u][4*q+1] = t.y;
                        zb[u][4*q+2] = t.z; zb[u][4*q+3] = t.w;
                    }
                }
#pragma unroll
                for (int v = 0; v < 4; ++v) {        // stream eb one v at a time:
                    float eb[16];                    // live = acc64 + zb64 + eb16
                    const float* src = &sm.es[tc + 32 * v][16 * b];
#pragma unroll
                    for (int q = 0; q < 4; ++q) {
                        float4 t = *(const float4*)(src + 4 * q);
                        eb[4*q+0] = t.x; eb[4*q+1] = t.y;
                        eb[4*q+2] = t.z; eb[4*q+3] = t.w;
                    }
#pragma unroll
                    for (int u = 0; u < 4; ++u)
#pragma unroll
                        for (int qq = 0; qq < 4; ++qq) {
                            const int q = 3 - qq;    // reverse chain: 12,8,4,0
#pragma unroll
                            for (int j = 0; j < 4; ++j) {
                                const int o = 4 * q + j;
                                acc[u][v][j] = acc[u][v][j] + zb[u][o] * eb[o];
                            }
                        }
                }
            }
        }

        // tile epilogue: hsum (SSE3 hadd grouping), dists, running first-min
#pragma unroll
        for (int u = 0; u < 4; ++u)
#pragma unroll
            for (int v = 0; v < 4; ++v) {
                const int k = ct * KT + tc + 32 * v;   // ascending k per thread
                float B = (acc[u][v][0] + acc[u][v][1]) + (acc[u][v][2] + acc[u][v][3]);
                float dist = (sm.A[tr + 16 * u] - 2.0f * B) + sm.C[k];
                if (dist < bv[u]) { bv[u] = dist; bi[u] = k; }   // strict <: first min
            }
    }

    // ---- cross-thread merge per row (index tiebreak = np.argmin first-min) ----
#pragma unroll
    for (int u = 0; u < 4; ++u) {
        const int r = tr + 16 * u;
        sm.s1v[r][tc] = bv[u];
        sm.s1i[r][tc] = bi[u];
    }
    __syncthreads();

    if (tid < RM) {
        float best = sm.s1v[tid][0];
        int   bidx = sm.s1i[tid][0];
        for (int t = 1; t < 32; ++t) {
            float v = sm.s1v[tid][t];
            int   i = sm.s1i[tid][t];
            if (v < best || (v == best && i < bidx)) { best = v; bidx = i; }
        }
        sm.bestk[tid] = bidx;
    }
    __syncthreads();

    // ---- outputs: z_q_st = fl(z + fl(zq - z)), z_q = zq; z comes from LDS copy ----
    {
        const int row = tid >> 3, q0 = tid & 7;
        const int k = sm.bestk[row];
        const float* zr = &sm.zs[row][0];
        const float* ek = cb + (size_t)k * DIM;
        float* o0 = out + (size_t)(r0 + row) * DIM;
        float* o1 = out + (size_t)NROWS * DIM + (size_t)(r0 + row) * DIM;
#pragma unroll
        for (int p = 0; p < 8; ++p) {
            int q = q0 + 8 * p;
            float4 zv = *(const float4*)(zr + 4 * q);
            float4 ev = *(const float4*)(ek + 4 * q);
            float4 st;
            st.x = zv.x + (ev.x - zv.x);
            st.y = zv.y + (ev.y - zv.y);
            st.z = zv.z + (ev.z - zv.z);
            st.w = zv.w + (ev.w - zv.w);
            *(float4*)(o0 + 4 * q) = st;
            *(float4*)(o1 + 4 * q) = ev;
        }
    }
}

extern "C" void kernel_launch(void* const* d_in, const int* in_sizes, int n_in,
                              void* d_out, int out_size, void* d_ws, size_t ws_size,
                              hipStream_t stream) {
    const float* z  = (const float*)d_in[0];   // z_e      [131072, 256] fp32
    const float* cb = (const float*)d_in[1];   // codebook [512, 256]    fp32
    float* out = (float*)d_out;                // (z_q_st, z_q) concat

    dim3 grid(NROWS / RM);
    dim3 block(NTHR);
    vq_np_faithful<<<grid, block, 0, stream>>>(z, cb, out);
}